// Round 6
// baseline (479.241 us; speedup 1.0000x reference)
//
#include <hip/hip_runtime.h>
#include <math.h>
#include <stdint.h>

#define VOL 262144        // 64^3
#define EPSF 1e-5f

typedef _Float16 half4_t __attribute__((ext_vector_type(4)));
typedef _Float16 half8 __attribute__((ext_vector_type(8)));
typedef float floatx4 __attribute__((ext_vector_type(4)));

__device__ __forceinline__ float waveReduceSum(float v) {
    #pragma unroll
    for (int off = 32; off > 0; off >>= 1) v += __shfl_down(v, off);
    return v;
}

// pack two fp32 -> fp16x2 in one instr
__device__ __forceinline__ uint32_t pk2(float a, float b) {
    uint32_t r;
    asm("v_cvt_pkrtz_f16_f32 %0, %1, %2" : "=v"(r) : "v"(a), "v"(b));
    return r;
}

// ---------------------------------------------------------------------------
// K0: weight prep -> MFMA B-fragments for mfma_f32_16x16x32_f16.
// wB[ks][lane][j]: k = ks*32 + (lane>>4)*8 + j maps to tap t = ks*4+(lane>>4),
// ic = j; n = lane&15 = oc (cols 8..15 zero; taps >= 27 zero).
// ---------------------------------------------------------------------------
__global__ void k_wprep(const float* __restrict__ w3, _Float16* __restrict__ wB) {
    int i = blockIdx.x * 256 + threadIdx.x;
    if (i < 3584) {
        int j = i & 7;
        int lane = (i >> 3) & 63;
        int ks = i >> 9;
        int oc = lane & 15;
        int t = ks * 4 + (lane >> 4);
        float v = 0.f;
        if (oc < 8 && t < 27) v = w3[(oc * 8 + j) * 27 + t];
        wB[i] = (_Float16)v;
    }
}

// ---------------------------------------------------------------------------
// K1: directional pool SUMS. 2048 blocks: r = blk>>4, p4 = blk&15 (4 d-slices).
// ---------------------------------------------------------------------------
__global__ void k_pools(const float* __restrict__ x, float* __restrict__ catS) {
    int r = blockIdx.x >> 4, p4 = blockIdx.x & 15;
    const float* base = x + (size_t)r * VOL + ((size_t)(p4 * 4) << 12);
    __shared__ float sd[4], sh[64], sw[64];
    int tid = threadIdx.x;
    if (tid < 4) sd[tid] = 0.f;
    if (tid < 64) { sh[tid] = 0.f; sw[tid] = 0.f; }
    __syncthreads();
    int w4 = (tid & 15) * 4;
    int hr = tid >> 4;
    int lane = tid & 63;
    float dacc[4] = {0.f, 0.f, 0.f, 0.f};
    float hacc[4] = {0.f, 0.f, 0.f, 0.f};
    float wacc[4] = {0.f, 0.f, 0.f, 0.f};
    #pragma unroll
    for (int p = 0; p < 4; p++) {
        const float* pd = base + (p << 12);
        #pragma unroll
        for (int j = 0; j < 4; j++) {
            float4 v = *(const float4*)(pd + ((hr + j * 16) << 6) + w4);
            float s = v.x + v.y + v.z + v.w;
            dacc[p] += s; hacc[j] += s;
            wacc[0] += v.x; wacc[1] += v.y; wacc[2] += v.z; wacc[3] += v.w;
        }
    }
    #pragma unroll
    for (int p = 0; p < 4; p++) {
        float s = waveReduceSum(dacc[p]);
        if (lane == 0) atomicAdd(&sd[p], s);
    }
    #pragma unroll
    for (int j = 0; j < 4; j++) {
        float hv = hacc[j];
        hv += __shfl_xor(hv, 1); hv += __shfl_xor(hv, 2);
        hv += __shfl_xor(hv, 4); hv += __shfl_xor(hv, 8);
        if ((lane & 15) == 0) atomicAdd(&sh[hr + j * 16], hv);
    }
    #pragma unroll
    for (int k = 0; k < 4; k++) {
        float wv = wacc[k];
        wv += __shfl_xor(wv, 16); wv += __shfl_xor(wv, 32);
        if (lane < 16) atomicAdd(&sw[w4 + k], wv);
    }
    __syncthreads();
    float* o = catS + (size_t)r * 192;
    if (tid < 4)                       atomicAdd(&o[p4 * 4 + tid], sd[tid]);
    else if (tid >= 64 && tid < 128)   atomicAdd(&o[64 + tid - 64], sh[tid - 64]);
    else if (tid >= 128 && tid < 192)  atomicAdd(&o[128 + tid - 128], sw[tid - 128]);
}

// ---------------------------------------------------------------------------
// K2a: BN stats of hwd. Single block. attnp[0..7]=scale, [8..15]=shift.
// ---------------------------------------------------------------------------
__global__ void k_attn_stats(const float* __restrict__ catS, const float* __restrict__ w1,
                             const float* __restrict__ b1, const float* __restrict__ g1,
                             const float* __restrict__ be1, float* __restrict__ attnp) {
    __shared__ float r1[256], r2[256];
    __shared__ float wsm[64];
    int tid = threadIdx.x;
    if (tid < 64) wsm[tid] = w1[tid] * (1.f / 4096.f);
    __syncthreads();
    int o = tid >> 5, j = tid & 31;
    float s1 = 0.f, s2 = 0.f;
    for (int idx = j; idx < 3072; idx += 32) {
        int bgI = idx / 192, s = idx - bgI * 192;
        const float* cp = catS + (size_t)bgI * 1536 + s;
        float h = b1[o];
        #pragma unroll
        for (int i = 0; i < 8; i++) h += wsm[o * 8 + i] * cp[i * 192];
        s1 += h; s2 += h * h;
    }
    r1[tid] = s1; r2[tid] = s2;
    __syncthreads();
    for (int st = 16; st > 0; st >>= 1) {
        if (j < st) { r1[tid] += r1[tid + st]; r2[tid] += r2[tid + st]; }
        __syncthreads();
    }
    if (j == 0) {
        float mean = r1[tid] / 3072.f;
        float var  = r2[tid] / 3072.f - mean * mean;
        float sc = g1[o] * rsqrtf(var + EPSF);
        attnp[o] = sc; attnp[8 + o] = be1[o] - mean * sc;
    }
}

// K2b: apply BN+relu+sigmoid -> a.
__global__ void k_attn_apply(const float* __restrict__ catS, const float* __restrict__ w1,
                             const float* __restrict__ b1, const float* __restrict__ attnp,
                             float* __restrict__ aout) {
    __shared__ float wsm[64];
    int tid = threadIdx.x;
    if (tid < 64) wsm[tid] = w1[tid] * (1.f / 4096.f);
    __syncthreads();
    int e = blockIdx.x * 256 + tid;
    int bgI = e / 1536;
    int rem = e - bgI * 1536;
    int oo = rem / 192;
    int s = rem - oo * 192;
    const float* cp = catS + (size_t)bgI * 1536 + s;
    float h = b1[oo];
    #pragma unroll
    for (int i = 0; i < 8; i++) h += wsm[oo * 8 + i] * cp[i * 192];
    float v = attnp[oo] * h + attnp[8 + oo];
    v = fmaxf(v, 0.f);
    aout[e] = 1.f / (1.f + __expf(-v));
}

// ---------------------------------------------------------------------------
// K4: 3x3x3 SAME conv as implicit GEMM on MFMA (mfma_f32_16x16x32_f16),
// GroupNorm raw sums fused into staging. R4 pipeline (stage d+1 -> sync ->
// compute d). Conflict fixes:
//   - WSTRIDE 67 (odd, 3 mod 8): ds_write_b128 covers all 32 banks.
//   - A-profiles NOT in LDS: A_d via wave-uniform scalar loads from global;
//     A_h / A_w fixed per thread -> preloaded in VGPRs (48 regs).
// LDS = 3*19296 + 768 = 58656 B <= 64000 proven 2-blocks/CU threshold.
// Grid 512 = bg(16) x ht(4) x dc(8). Block = 256 thr = 4 waves.
// ---------------------------------------------------------------------------
#define WSTRIDE 67
#define SLICE_B (18 * WSTRIDE * 16)   // 19296 B per d-slice

// stage one item: global load -> GN acc (register A-profiles) -> pack -> LDS
__device__ __forceinline__ void stage_item(const float* __restrict__ pd, bool ok, bool acc,
                                           int hl, int w4, int gh, char* sb,
                                           const float* __restrict__ ad,
                                           const float* __restrict__ Ah,
                                           const float (*__restrict__ Aw)[4],
                                           float* g1, float* g2) {
    float vv[8][4];
    #pragma unroll
    for (int ic = 0; ic < 8; ic++) {
        float4 t = make_float4(0.f, 0.f, 0.f, 0.f);
        if (ok) t = *(const float4*)(pd + ((size_t)ic << 18) + (gh << 6) + w4);
        vv[ic][0] = t.x; vv[ic][1] = t.y; vv[ic][2] = t.z; vv[ic][3] = t.w;
    }
    if (acc) {
        #pragma unroll
        for (int ic = 0; ic < 8; ic++) {
            float adh = ad[ic] * Ah[ic];
            float y0 = vv[ic][0] * adh * Aw[ic][0];
            float y1 = vv[ic][1] * adh * Aw[ic][1];
            float y2 = vv[ic][2] * adh * Aw[ic][2];
            float y3 = vv[ic][3] * adh * Aw[ic][3];
            g1[ic] += y0 + y1 + y2 + y3;
            g2[ic] += y0 * y0 + y1 * y1 + y2 * y2 + y3 * y3;
        }
    }
    char* wp = sb + ((hl * WSTRIDE) + 1 + w4) * 16;
    #pragma unroll
    for (int j = 0; j < 4; j++) {
        uint4 q;
        q.x = pk2(vv[0][j], vv[1][j]);
        q.y = pk2(vv[2][j], vv[3][j]);
        q.z = pk2(vv[4][j], vv[5][j]);
        q.w = pk2(vv[6][j], vv[7][j]);
        *(uint4*)(wp + j * 16) = q;
    }
}

__device__ __forceinline__ void stage_slice(const float* __restrict__ xb, int dd,
                                            char* smem, int slot, int h0, int tid,
                                            const float* __restrict__ aG, int d0,
                                            float* g1, float* g2,
                                            const float* __restrict__ Ah0,
                                            const float* __restrict__ Ah1,
                                            const float (*__restrict__ Aw)[4]) {
    char* sb = smem + slot * SLICE_B;
    bool dok = (dd >= 0) && (dd < 64);
    bool core = (dd >= d0) && (dd < d0 + 8);
    const float* pd = xb + ((size_t)(dd & 63) << 12);
    float ad[8];
    if (core) {
        #pragma unroll
        for (int ic = 0; ic < 8; ic++) ad[ic] = aG[ic * 192 + dd];   // uniform -> s_load
    } else {
        #pragma unroll
        for (int ic = 0; ic < 8; ic++) ad[ic] = 0.f;
    }
    int hl0 = tid >> 4, w4 = (tid & 15) << 2;
    int gh0 = h0 - 1 + hl0;
    bool ok0 = dok && (gh0 >= 0);              // gh0 <= 62 < 64 always
    bool acc0 = core && (hl0 >= 1);            // hl0 <= 15 always
    stage_item(pd, ok0, acc0, hl0, w4, gh0, sb, ad, Ah0, Aw, g1, g2);
    if (tid < 32) {
        int hl1 = 16 + (tid >> 4);
        int gh1 = h0 - 1 + hl1;                // >= 15 always
        bool ok1 = dok && (gh1 < 64);
        bool acc1 = core && (hl1 <= 16);
        stage_item(pd, ok1, acc1, hl1, w4, gh1, sb, ad, Ah1, Aw, g1, g2);
    }
}

__global__ __launch_bounds__(256) void k_conv(const float* __restrict__ x,
                                              const _Float16* __restrict__ wB,
                                              const float* __restrict__ b3,
                                              const float* __restrict__ a,
                                              _Float16* __restrict__ x2h,
                                              float* __restrict__ stats,
                                              float* __restrict__ gs) {
    __shared__ __align__(16) char smem[3 * SLICE_B + 768];
    float* wred = (float*)(smem + 3 * SLICE_B);         // 128 floats (BN)
    float* wgn  = wred + 128;                           // 64 floats (GN)
    int blk = blockIdx.x;
    int bg = blk >> 5;
    int rem = blk & 31;
    int ht = rem >> 3;
    int dc = rem & 7;
    int h0 = ht << 4;
    int d0 = dc << 3;
    int tid = threadIdx.x;
    int lane = tid & 63, wid = tid >> 6;
    int lm = lane & 15, lg = lane >> 4;
    const float* xb = x + ((size_t)bg << 21);
    const float* aG = a + (size_t)bg * 1536;

    // B fragments (7 k-steps x 16B/lane)
    half8 bfr[7];
    #pragma unroll
    for (int ks = 0; ks < 7; ks++)
        bfr[ks] = *(const half8*)(wB + (ks << 9) + (lane << 3));

    float b3v = (lm < 8) ? b3[lm] : 0.f;

    // per-thread A_h / A_w register profiles (fixed gh/w4 per thread)
    int phl0 = tid >> 4, pw4 = (tid & 15) << 2;
    int pgh0 = h0 - 1 + phl0;
    int pgh1 = h0 + 15 + (tid >> 4);   // = h0-1+(16+(tid>>4))
    float Ah0[8], Ah1[8], Aw[8][4];
    #pragma unroll
    for (int ic = 0; ic < 8; ic++) {
        Ah0[ic] = (pgh0 >= 0) ? aG[ic * 192 + 64 + pgh0] : 0.f;
        Ah1[ic] = (pgh1 < 64) ? aG[ic * 192 + 64 + pgh1] : 0.f;
        #pragma unroll
        for (int k = 0; k < 4; k++) Aw[ic][k] = aG[ic * 192 + 128 + pw4 + k];
    }

    // per-lane tap -> LDS relative offsets (ky,kx,lm folded; wid folds h base)
    int rel[7], kzv[7];
    #pragma unroll
    for (int ks = 0; ks < 7; ks++) {
        int t = ks * 4 + lg; if (t > 26) t = 26;   // pad tap: B rows are zero
        int kz = t / 9, r9 = t - kz * 9;
        int ky = r9 / 3, kx = r9 - ky * 3;
        kzv[ks] = kz;
        rel[ks] = (((ky + wid * 4) * WSTRIDE) + kx + lm) << 4;
    }

    // zero halo columns (quads 0, 65) of all 3 slots, once
    for (int u = tid; u < 108; u += 256) {
        int s = u / 36, r2 = u - s * 36;
        int hh = r2 >> 1, side = r2 & 1;
        uint4 z; z.x = 0; z.y = 0; z.z = 0; z.w = 0;
        *(uint4*)(smem + s * SLICE_B + ((hh * WSTRIDE) + side * 65) * 16) = z;
    }

    size_t eb = (((size_t)(bg * 8 + lm)) << 18) + ((size_t)(h0 + wid * 4) << 6) + (lg << 2);
    bool ocok = lm < 8;
    float ps = 0.f, pq = 0.f;
    float g1[8] = {0.f, 0.f, 0.f, 0.f, 0.f, 0.f, 0.f, 0.f};
    float g2[8] = {0.f, 0.f, 0.f, 0.f, 0.f, 0.f, 0.f, 0.f};

    stage_slice(xb, d0 - 1, smem, (d0 + 2) % 3, h0, tid, aG, d0, g1, g2, Ah0, Ah1, Aw);
    stage_slice(xb, d0,     smem, d0 % 3,       h0, tid, aG, d0, g1, g2, Ah0, Ah1, Aw);
    __syncthreads();

    for (int i = 0; i < 8; i++) {
        int d = d0 + i;
        stage_slice(xb, d + 1, smem, (d + 1) % 3, h0, tid, aG, d0, g1, g2, Ah0, Ah1, Aw);
        __syncthreads();
        int u0 = ((d + 2) % 3) * SLICE_B;   // slice dd = d-1
        int u1 = (d % 3) * SLICE_B;         // slice dd = d
        int u2 = ((d + 1) % 3) * SLICE_B;   // slice dd = d+1
        int ab[7];
        #pragma unroll
        for (int ks = 0; ks < 7; ks++)
            ab[ks] = (kzv[ks] == 0 ? u0 : (kzv[ks] == 1 ? u1 : u2)) + rel[ks];
        #pragma unroll
        for (int ri = 0; ri < 4; ri++) {
            #pragma unroll
            for (int wt = 0; wt < 4; wt++) {
                floatx4 acc = {b3v, b3v, b3v, b3v};
                #pragma unroll
                for (int ks = 0; ks < 7; ks++) {
                    half8 af = *(const half8*)(smem + ab[ks] + ((ri * WSTRIDE + wt * 16) << 4));
                    acc = __builtin_amdgcn_mfma_f32_16x16x32_f16(af, bfr[ks], acc, 0, 0, 0);
                }
                uint32_t q0 = pk2(acc[0], acc[1]);
                uint32_t q1 = pk2(acc[2], acc[3]);
                if (ocok) {
                    uint2 st; st.x = q0; st.y = q1;
                    *(uint2*)(x2h + eb + ((size_t)d << 12) + (ri << 6) + (wt << 4)) = st;
                }
                ps += acc[0] + acc[1] + acc[2] + acc[3];
                pq += acc[0] * acc[0] + acc[1] * acc[1] + acc[2] * acc[2] + acc[3] * acc[3];
            }
        }
        __syncthreads();
    }

    // BN sums: lane's oc = lm; reduce the 4 lg-replica groups, then cross-wave
    ps += __shfl_xor(ps, 16); ps += __shfl_xor(ps, 32);
    pq += __shfl_xor(pq, 16); pq += __shfl_xor(pq, 32);
    if (lane < 16) { wred[wid * 32 + lm] = ps; wred[wid * 32 + 16 + lm] = pq; }
    // GN sums: full-wave reduce per ic, then cross-wave via LDS
    #pragma unroll
    for (int ic = 0; ic < 8; ic++) {
        float r1v = waveReduceSum(g1[ic]);
        float r2v = waveReduceSum(g2[ic]);
        if (lane == 0) { wgn[wid * 16 + ic] = r1v; wgn[wid * 16 + 8 + ic] = r2v; }
    }
    __syncthreads();
    if (tid < 8) {
        float t1 = wred[tid] + wred[32 + tid] + wred[64 + tid] + wred[96 + tid];
        float t2 = wred[16 + tid] + wred[48 + tid] + wred[80 + tid] + wred[112 + tid];
        atomicAdd(&stats[tid], t1);
        atomicAdd(&stats[8 + tid], t2);
        float q1 = wgn[tid] + wgn[16 + tid] + wgn[32 + tid] + wgn[48 + tid];
        float q2 = wgn[8 + tid] + wgn[24 + tid] + wgn[40 + tid] + wgn[56 + tid];
        atomicAdd(&gs[bg * 8 + tid], q1);
        atomicAdd(&gs[128 + bg * 8 + tid], q2);
    }
}

// K5: finalize BN3 scale/shift; x11 = softmax(gn_b).
__global__ void k_finalize(const float* __restrict__ stats, const float* __restrict__ g3,
                           const float* __restrict__ be3, const float* __restrict__ gnb,
                           float* __restrict__ bnp, float* __restrict__ x11) {
    int tid = threadIdx.x;
    if (tid < 8) {
        float N = 16.f * (float)VOL;
        float mean = stats[tid] / N;
        float var  = stats[8 + tid] / N - mean * mean;
        float sc = g3[tid] * rsqrtf(var + EPSF);
        bnp[tid] = sc; bnp[8 + tid] = be3[tid] - mean * sc;
    }
    if (tid == 0) {
        float m = -1e30f;
        for (int c = 0; c < 8; c++) m = fmaxf(m, gnb[c]);
        float e[8], sum = 0.f;
        for (int c = 0; c < 8; c++) { e[c] = __expf(gnb[c] - m); sum += e[c]; }
        for (int c = 0; c < 8; c++) x11[c] = e[c] / sum;
    }
}

// K6: per-row sum of relu(bn(x2h)) -> mrelu. 1024 blocks, half4 reads.
__global__ void k_relumean(const _Float16* __restrict__ x2h, const float* __restrict__ bnp,
                           float* __restrict__ mrelu) {
    int blk = blockIdx.x;
    int r = blk >> 3, part = blk & 7;
    int cc = r & 7;
    float sc = bnp[cc], sh = bnp[8 + cc];
    const half4_t* p = (const half4_t*)(x2h + (size_t)r * VOL + (size_t)part * 32768);
    int tid = threadIdx.x;
    float s = 0.f;
    for (int it = 0; it < 32; it++) {
        half4_t v = p[it * 256 + tid];
        s += fmaxf(sc * (float)v.x + sh, 0.f) + fmaxf(sc * (float)v.y + sh, 0.f)
           + fmaxf(sc * (float)v.z + sh, 0.f) + fmaxf(sc * (float)v.w + sh, 0.f);
    }
    s = waveReduceSum(s);
    __shared__ float wred[4];
    int lane = tid & 63, wid = tid >> 6;
    if (lane == 0) wred[wid] = s;
    __syncthreads();
    if (tid == 0) atomicAdd(&mrelu[r], wred[0] + wred[1] + wred[2] + wred[3]);
}

// K6b: x21[bg][c] = softmax_c(mrelu[bg*8+c]/VOL)
__global__ void k_soft21(const float* __restrict__ mrelu, float* __restrict__ x21) {
    int bg = threadIdx.x;
    if (bg < 16) {
        float v[8], m = -1e30f;
        for (int c = 0; c < 8; c++) { v[c] = mrelu[bg * 8 + c] / (float)VOL; m = fmaxf(m, v[c]); }
        float sum = 0.f;
        for (int c = 0; c < 8; c++) { v[c] = __expf(v[c] - m); sum += v[c]; }
        for (int c = 0; c < 8; c++) x21[bg * 8 + c] = v[c] / sum;
    }
}

// ---------------------------------------------------------------------------
// K7: final fused: weights = x11·x22 + x21·x12; out = x * sigmoid(weights).
// ---------------------------------------------------------------------------
__global__ void k_final(const float* __restrict__ x, const _Float16* __restrict__ x2h,
                        const float* __restrict__ a, const float* __restrict__ bnp,
                        const float* __restrict__ x11g, const float* __restrict__ x21g,
                        const float* __restrict__ gs, const float* __restrict__ gng,
                        const float* __restrict__ gnb, float* __restrict__ out) {
    int bg = blockIdx.x >> 8;
    int seg = blockIdx.x & 255;
    int tid = threadIdx.x;
    __shared__ float sa[1536];
    __shared__ float sc_[8], sh_[8], sx11[8], sx21[8], sgsc[8], sgsh[8];
    const float* ap = a + (size_t)bg * 1536;
    for (int i = tid; i < 1536; i += 256) sa[i] = ap[i];
    if (tid < 8) {
        int r = bg * 8 + tid;
        sc_[tid] = bnp[tid]; sh_[tid] = bnp[8 + tid];
        sx11[tid] = x11g[tid]; sx21[tid] = x21g[r];
        float mean = gs[r] / (float)VOL;
        float var  = gs[128 + r] / (float)VOL - mean * mean;
        float gr = rsqrtf(var + EPSF) * gng[tid];
        sgsc[tid] = gr; sgsh[tid] = gnb[tid] - mean * gr;
    }
    __syncthreads();
    int n = (seg * 256 + tid) * 4;
    int d = n >> 12, h = (n >> 6) & 63, w = n & 63;
    size_t base = ((size_t)bg << 21) + n;
    float4 xr[8];
    float w0 = 0.f, w1 = 0.f, w2 = 0.f, w3 = 0.f;
    #pragma unroll
    for (int c = 0; c < 8; c++) {
        size_t idx = base + ((size_t)c << 18);
        float4 xv = *(const float4*)(x + idx);
        half4_t v2 = *(const half4_t*)(x2h + idx);
        xr[c] = xv;
        float adh = sa[c * 192 + d] * sa[c * 192 + 64 + h] * sgsc[c];
        float x22_0 = fmaxf(sc_[c] * (float)v2.x + sh_[c], 0.f);
        float x22_1 = fmaxf(sc_[c] * (float)v2.y + sh_[c], 0.f);
        float x22_2 = fmaxf(sc_[c] * (float)v2.z + sh_[c], 0.f);
        float x22_3 = fmaxf(sc_[c] * (float)v2.w + sh_[c], 0.f);
        float x12_0 = xv.x * (adh * sa[c * 192 + 128 + w])     + sgsh[c];
        float x12_1 = xv.y * (adh * sa[c * 192 + 128 + w + 1]) + sgsh[c];
        float x12_2 = xv.z * (adh * sa[c * 192 + 128 + w + 2]) + sgsh[c];
        float x12_3 = xv.w * (adh * sa[c * 192 + 128 + w + 3]) + sgsh[c];
        w0 += sx11[c] * x22_0 + sx21[c] * x12_0;
        w1 += sx11[c] * x22_1 + sx21[c] * x12_1;
        w2 += sx11[c] * x22_2 + sx21[c] * x12_2;
        w3 += sx11[c] * x22_3 + sx21[c] * x12_3;
    }
    float s0 = 1.f / (1.f + __expf(-w0));
    float s1 = 1.f / (1.f + __expf(-w1));
    float s2 = 1.f / (1.f + __expf(-w2));
    float s3 = 1.f / (1.f + __expf(-w3));
    #pragma unroll
    for (int c = 0; c < 8; c++) {
        float4 o;
        o.x = xr[c].x * s0; o.y = xr[c].y * s1; o.z = xr[c].z * s2; o.w = xr[c].w * s3;
        *(float4*)(out + base + ((size_t)c << 18)) = o;
    }
}

extern "C" void kernel_launch(void* const* d_in, const int* in_sizes, int n_in,
                              void* d_out, int out_size, void* d_ws, size_t ws_size,
                              hipStream_t stream) {
    const float* x   = (const float*)d_in[0];
    const float* w1  = (const float*)d_in[1];
    const float* b1  = (const float*)d_in[2];
    const float* g1  = (const float*)d_in[3];
    const float* be1 = (const float*)d_in[4];
    const float* w3  = (const float*)d_in[5];
    const float* b3  = (const float*)d_in[6];
    const float* g3  = (const float*)d_in[7];
    const float* be3 = (const float*)d_in[8];
    const float* gng = (const float*)d_in[9];
    const float* gnb = (const float*)d_in[10];
    float* out = (float*)d_out;

    float* wsf       = (float*)d_ws;
    _Float16* x2h    = (_Float16*)d_ws;       // 33554432 halfs = 16777216 float-slots
    // zeroed region (contiguous): catS, stats, gs, mrelu
    float* catS   = wsf + 16777216;           // 24576
    float* stats  = catS + 24576;             // 16
    float* gs     = stats + 16;               // 256
    float* mrelu  = gs + 256;                 // 128
    // non-zeroed small buffers
    float* a      = mrelu + 128;              // 24576
    float* bnp    = a + 24576;                // 16
    float* x11    = bnp + 16;                 // 8
    float* x21    = x11 + 8;                  // 128
    float* attnp  = x21 + 128;                // 16
    _Float16* wB  = (_Float16*)(attnp + 16);  // 3584 halfs (MFMA B-fragments)

    hipMemsetAsync(catS, 0, (24576 + 16 + 256 + 128) * sizeof(float), stream);

    k_wprep     <<<14, 256, 0, stream>>>(w3, wB);
    k_pools     <<<2048, 256, 0, stream>>>(x, catS);
    k_attn_stats<<<1, 256, 0, stream>>>(catS, w1, b1, g1, be1, attnp);
    k_attn_apply<<<96, 256, 0, stream>>>(catS, w1, b1, attnp, a);
    k_conv      <<<512, 256, 0, stream>>>(x, wB, b3, a, x2h, stats, gs);
    k_finalize  <<<1, 64, 0, stream>>>(stats, g3, be3, gnb, bnp, x11);
    k_relumean  <<<1024, 256, 0, stream>>>(x2h, bnp, mrelu);
    k_soft21    <<<1, 64, 0, stream>>>(mrelu, x21);
    k_final     <<<4096, 256, 0, stream>>>(x, x2h, a, bnp, x11, x21, gs, gng, gnb, out);
}

// Round 7
// 445.630 us; speedup vs baseline: 1.0754x; 1.0754x over previous
//
#include <hip/hip_runtime.h>
#include <math.h>
#include <stdint.h>

#define VOL 262144        // 64^3
#define EPSF 1e-5f

typedef _Float16 half4_t __attribute__((ext_vector_type(4)));
typedef _Float16 half8 __attribute__((ext_vector_type(8)));
typedef float floatx4 __attribute__((ext_vector_type(4)));

__device__ __forceinline__ float waveReduceSum(float v) {
    #pragma unroll
    for (int off = 32; off > 0; off >>= 1) v += __shfl_down(v, off);
    return v;
}

// pack two fp32 -> fp16x2 in one instr
__device__ __forceinline__ uint32_t pk2(float a, float b) {
    uint32_t r;
    asm("v_cvt_pkrtz_f16_f32 %0, %1, %2" : "=v"(r) : "v"(a), "v"(b));
    return r;
}

// ---------------------------------------------------------------------------
// K0: weight prep -> MFMA B-fragments for mfma_f32_16x16x32_f16.
// wB[ks][lane][j]: k = ks*32 + (lane>>4)*8 + j maps to tap t = ks*4+(lane>>4),
// ic = j; n = lane&15 = oc (cols 8..15 zero; taps >= 27 zero).
// ---------------------------------------------------------------------------
__global__ void k_wprep(const float* __restrict__ w3, _Float16* __restrict__ wB) {
    int i = blockIdx.x * 256 + threadIdx.x;
    if (i < 3584) {
        int j = i & 7;
        int lane = (i >> 3) & 63;
        int ks = i >> 9;
        int oc = lane & 15;
        int t = ks * 4 + (lane >> 4);
        float v = 0.f;
        if (oc < 8 && t < 27) v = w3[(oc * 8 + j) * 27 + t];
        wB[i] = (_Float16)v;
    }
}

// ---------------------------------------------------------------------------
// K1: directional pool SUMS. 2048 blocks: r = blk>>4, p4 = blk&15 (4 d-slices).
// ---------------------------------------------------------------------------
__global__ void k_pools(const float* __restrict__ x, float* __restrict__ catS) {
    int r = blockIdx.x >> 4, p4 = blockIdx.x & 15;
    const float* base = x + (size_t)r * VOL + ((size_t)(p4 * 4) << 12);
    __shared__ float sd[4], sh[64], sw[64];
    int tid = threadIdx.x;
    if (tid < 4) sd[tid] = 0.f;
    if (tid < 64) { sh[tid] = 0.f; sw[tid] = 0.f; }
    __syncthreads();
    int w4 = (tid & 15) * 4;
    int hr = tid >> 4;
    int lane = tid & 63;
    float dacc[4] = {0.f, 0.f, 0.f, 0.f};
    float hacc[4] = {0.f, 0.f, 0.f, 0.f};
    float wacc[4] = {0.f, 0.f, 0.f, 0.f};
    #pragma unroll
    for (int p = 0; p < 4; p++) {
        const float* pd = base + (p << 12);
        #pragma unroll
        for (int j = 0; j < 4; j++) {
            float4 v = *(const float4*)(pd + ((hr + j * 16) << 6) + w4);
            float s = v.x + v.y + v.z + v.w;
            dacc[p] += s; hacc[j] += s;
            wacc[0] += v.x; wacc[1] += v.y; wacc[2] += v.z; wacc[3] += v.w;
        }
    }
    #pragma unroll
    for (int p = 0; p < 4; p++) {
        float s = waveReduceSum(dacc[p]);
        if (lane == 0) atomicAdd(&sd[p], s);
    }
    #pragma unroll
    for (int j = 0; j < 4; j++) {
        float hv = hacc[j];
        hv += __shfl_xor(hv, 1); hv += __shfl_xor(hv, 2);
        hv += __shfl_xor(hv, 4); hv += __shfl_xor(hv, 8);
        if ((lane & 15) == 0) atomicAdd(&sh[hr + j * 16], hv);
    }
    #pragma unroll
    for (int k = 0; k < 4; k++) {
        float wv = wacc[k];
        wv += __shfl_xor(wv, 16); wv += __shfl_xor(wv, 32);
        if (lane < 16) atomicAdd(&sw[w4 + k], wv);
    }
    __syncthreads();
    float* o = catS + (size_t)r * 192;
    if (tid < 4)                       atomicAdd(&o[p4 * 4 + tid], sd[tid]);
    else if (tid >= 64 && tid < 128)   atomicAdd(&o[64 + tid - 64], sh[tid - 64]);
    else if (tid >= 128 && tid < 192)  atomicAdd(&o[128 + tid - 128], sw[tid - 128]);
}

// ---------------------------------------------------------------------------
// K2a: BN stats of hwd. Single block. attnp[0..7]=scale, [8..15]=shift.
// ---------------------------------------------------------------------------
__global__ void k_attn_stats(const float* __restrict__ catS, const float* __restrict__ w1,
                             const float* __restrict__ b1, const float* __restrict__ g1,
                             const float* __restrict__ be1, float* __restrict__ attnp) {
    __shared__ float r1[256], r2[256];
    __shared__ float wsm[64];
    int tid = threadIdx.x;
    if (tid < 64) wsm[tid] = w1[tid] * (1.f / 4096.f);
    __syncthreads();
    int o = tid >> 5, j = tid & 31;
    float s1 = 0.f, s2 = 0.f;
    for (int idx = j; idx < 3072; idx += 32) {
        int bgI = idx / 192, s = idx - bgI * 192;
        const float* cp = catS + (size_t)bgI * 1536 + s;
        float h = b1[o];
        #pragma unroll
        for (int i = 0; i < 8; i++) h += wsm[o * 8 + i] * cp[i * 192];
        s1 += h; s2 += h * h;
    }
    r1[tid] = s1; r2[tid] = s2;
    __syncthreads();
    for (int st = 16; st > 0; st >>= 1) {
        if (j < st) { r1[tid] += r1[tid + st]; r2[tid] += r2[tid + st]; }
        __syncthreads();
    }
    if (j == 0) {
        float mean = r1[tid] / 3072.f;
        float var  = r2[tid] / 3072.f - mean * mean;
        float sc = g1[o] * rsqrtf(var + EPSF);
        attnp[o] = sc; attnp[8 + o] = be1[o] - mean * sc;
    }
}

// K2b: apply BN+relu+sigmoid -> a.
__global__ void k_attn_apply(const float* __restrict__ catS, const float* __restrict__ w1,
                             const float* __restrict__ b1, const float* __restrict__ attnp,
                             float* __restrict__ aout) {
    __shared__ float wsm[64];
    int tid = threadIdx.x;
    if (tid < 64) wsm[tid] = w1[tid] * (1.f / 4096.f);
    __syncthreads();
    int e = blockIdx.x * 256 + tid;
    int bgI = e / 1536;
    int rem = e - bgI * 1536;
    int oo = rem / 192;
    int s = rem - oo * 192;
    const float* cp = catS + (size_t)bgI * 1536 + s;
    float h = b1[oo];
    #pragma unroll
    for (int i = 0; i < 8; i++) h += wsm[oo * 8 + i] * cp[i * 192];
    float v = attnp[oo] * h + attnp[8 + oo];
    v = fmaxf(v, 0.f);
    aout[e] = 1.f / (1.f + __expf(-v));
}

// ---------------------------------------------------------------------------
// K4: 3x3x3 SAME conv as implicit GEMM on MFMA (mfma_f32_16x16x32_f16),
// GroupNorm raw sums fused into staging (R4-proven structure, re-tiled).
// h-tile 8 (+2 halo = 10 slice rows) -> LDS 37.6 KB -> 4 blocks/CU.
// Grid 1024 = bg(16) x ht(8) x dc(8). Block = 256 thr = 4 waves.
// Wave wid owns output rows wid*2 + {0,1}; per iter: 2x4 tiles x 7 MFMA.
// ---------------------------------------------------------------------------
#define WSTRIDE 66
#define SROWS 10
#define SLICE_B (SROWS * WSTRIDE * 16)   // 10560 B per d-slice

__device__ __forceinline__ void stage_slice(const float* __restrict__ xb, int dd,
                                            char* smem, int slot, int h0, int tid,
                                            const float* __restrict__ sA, int d0,
                                            float* g1, float* g2) {
    if (tid >= 160) return;
    char* sb = smem + slot * SLICE_B;
    bool dok = (dd >= 0) && (dd < 64);
    bool core = (dd >= d0) && (dd < d0 + 8);
    const float* pd = xb + ((size_t)(dd & 63) << 12);
    int hl = tid >> 4;
    int w4 = (tid & 15) << 2;
    int gh = h0 - 1 + hl;
    bool ok = dok && (gh >= 0) && (gh < 64);
    bool acc = core && (hl >= 1) && (hl <= 8);
    float vv[8][4];
    #pragma unroll
    for (int ic = 0; ic < 8; ic++) {
        float4 t = make_float4(0.f, 0.f, 0.f, 0.f);
        if (ok) t = *(const float4*)(pd + ((size_t)ic << 18) + (gh << 6) + w4);
        vv[ic][0] = t.x; vv[ic][1] = t.y; vv[ic][2] = t.z; vv[ic][3] = t.w;
    }
    if (acc) {
        #pragma unroll
        for (int ic = 0; ic < 8; ic++) {
            const float* Ap = sA + ic * 192;
            float ad = Ap[dd] * Ap[64 + gh];
            float y0 = vv[ic][0] * ad * Ap[128 + w4];
            float y1 = vv[ic][1] * ad * Ap[128 + w4 + 1];
            float y2 = vv[ic][2] * ad * Ap[128 + w4 + 2];
            float y3 = vv[ic][3] * ad * Ap[128 + w4 + 3];
            g1[ic] += y0 + y1 + y2 + y3;
            g2[ic] += y0 * y0 + y1 * y1 + y2 * y2 + y3 * y3;
        }
    }
    char* wp = sb + ((hl * WSTRIDE) + 1 + w4) * 16;
    #pragma unroll
    for (int j = 0; j < 4; j++) {
        uint4 q;
        q.x = pk2(vv[0][j], vv[1][j]);
        q.y = pk2(vv[2][j], vv[3][j]);
        q.z = pk2(vv[4][j], vv[5][j]);
        q.w = pk2(vv[6][j], vv[7][j]);
        *(uint4*)(wp + j * 16) = q;
    }
}

__global__ __launch_bounds__(256) void k_conv(const float* __restrict__ x,
                                              const _Float16* __restrict__ wB,
                                              const float* __restrict__ b3,
                                              const float* __restrict__ a,
                                              _Float16* __restrict__ x2h,
                                              float* __restrict__ stats,
                                              float* __restrict__ gs) {
    __shared__ __align__(16) char smem[3 * SLICE_B + 768 + 6144];
    float* wred = (float*)(smem + 3 * SLICE_B);         // 128 floats (BN)
    float* wgn  = wred + 128;                           // 64 floats (GN)
    float* sA   = (float*)(smem + 3 * SLICE_B + 768);   // 8 x 192 floats
    int blk = blockIdx.x;
    int bg = blk >> 6;
    int rem = blk & 63;
    int ht = rem >> 3;     // 0..7
    int dc = rem & 7;
    int h0 = ht << 3;
    int d0 = dc << 3;
    int tid = threadIdx.x;
    int lane = tid & 63, wid = tid >> 6;
    int lm = lane & 15, lg = lane >> 4;
    const float* xb = x + ((size_t)bg << 21);

    // B fragments (7 k-steps x 16B/lane)
    half8 bfr[7];
    #pragma unroll
    for (int ks = 0; ks < 7; ks++)
        bfr[ks] = *(const half8*)(wB + (ks << 9) + (lane << 3));

    float b3v = (lm < 8) ? b3[lm] : 0.f;

    // per-lane tap -> LDS relative offsets (ky,kx,lm folded; wid folds h base)
    int rel[7], kzv[7];
    #pragma unroll
    for (int ks = 0; ks < 7; ks++) {
        int t = ks * 4 + lg; if (t > 26) t = 26;   // pad tap: B rows are zero
        int kz = t / 9, r9 = t - kz * 9;
        int ky = r9 / 3, kx = r9 - ky * 3;
        kzv[ks] = kz;
        rel[ks] = (((ky + wid * 2) * WSTRIDE) + kx + lm) << 4;
    }

    // zero halo columns (quads 0, 65) of all 3 slots, once: 3*10*2 = 60
    if (tid < 60) {
        int s = tid / 20, r2 = tid - s * 20;
        int hh = r2 >> 1, side = r2 & 1;
        uint4 z; z.x = 0; z.y = 0; z.z = 0; z.w = 0;
        *(uint4*)(smem + s * SLICE_B + ((hh * WSTRIDE) + side * 65) * 16) = z;
    }
    // attention profiles for this bg (8 rows x 192)
    for (int i = tid; i < 1536; i += 256) sA[i] = a[(size_t)bg * 1536 + i];
    __syncthreads();   // sA ready before staging accumulates GN sums

    size_t eb = (((size_t)(bg * 8 + lm)) << 18) + ((size_t)(h0 + wid * 2) << 6) + (lg << 2);
    bool ocok = lm < 8;
    float ps = 0.f, pq = 0.f;
    float g1[8] = {0.f, 0.f, 0.f, 0.f, 0.f, 0.f, 0.f, 0.f};
    float g2[8] = {0.f, 0.f, 0.f, 0.f, 0.f, 0.f, 0.f, 0.f};

    stage_slice(xb, d0 - 1, smem, (d0 + 2) % 3, h0, tid, sA, d0, g1, g2);
    stage_slice(xb, d0,     smem, d0 % 3,       h0, tid, sA, d0, g1, g2);
    __syncthreads();

    for (int i = 0; i < 8; i++) {
        int d = d0 + i;
        stage_slice(xb, d + 1, smem, (d + 1) % 3, h0, tid, sA, d0, g1, g2);
        __syncthreads();
        int u0 = ((d + 2) % 3) * SLICE_B;   // slice dd = d-1
        int u1 = (d % 3) * SLICE_B;         // slice dd = d
        int u2 = ((d + 1) % 3) * SLICE_B;   // slice dd = d+1
        int ab[7];
        #pragma unroll
        for (int ks = 0; ks < 7; ks++)
            ab[ks] = (kzv[ks] == 0 ? u0 : (kzv[ks] == 1 ? u1 : u2)) + rel[ks];
        #pragma unroll
        for (int ri = 0; ri < 2; ri++) {
            #pragma unroll
            for (int wt = 0; wt < 4; wt++) {
                floatx4 acc = {b3v, b3v, b3v, b3v};
                #pragma unroll
                for (int ks = 0; ks < 7; ks++) {
                    half8 af = *(const half8*)(smem + ab[ks] + ((ri * WSTRIDE + wt * 16) << 4));
                    acc = __builtin_amdgcn_mfma_f32_16x16x32_f16(af, bfr[ks], acc, 0, 0, 0);
                }
                uint32_t q0 = pk2(acc[0], acc[1]);
                uint32_t q1 = pk2(acc[2], acc[3]);
                if (ocok) {
                    uint2 st; st.x = q0; st.y = q1;
                    *(uint2*)(x2h + eb + ((size_t)d << 12) + (ri << 6) + (wt << 4)) = st;
                }
                ps += acc[0] + acc[1] + acc[2] + acc[3];
                pq += acc[0] * acc[0] + acc[1] * acc[1] + acc[2] * acc[2] + acc[3] * acc[3];
            }
        }
        __syncthreads();
    }

    // BN sums: lane's oc = lm; reduce the 4 lg-replica groups, then cross-wave
    ps += __shfl_xor(ps, 16); ps += __shfl_xor(ps, 32);
    pq += __shfl_xor(pq, 16); pq += __shfl_xor(pq, 32);
    if (lane < 16) { wred[wid * 32 + lm] = ps; wred[wid * 32 + 16 + lm] = pq; }
    // GN sums: full-wave reduce per ic, then cross-wave via LDS
    #pragma unroll
    for (int ic = 0; ic < 8; ic++) {
        float r1v = waveReduceSum(g1[ic]);
        float r2v = waveReduceSum(g2[ic]);
        if (lane == 0) { wgn[wid * 16 + ic] = r1v; wgn[wid * 16 + 8 + ic] = r2v; }
    }
    __syncthreads();
    if (tid < 8) {
        float t1 = wred[tid] + wred[32 + tid] + wred[64 + tid] + wred[96 + tid];
        float t2 = wred[16 + tid] + wred[48 + tid] + wred[80 + tid] + wred[112 + tid];
        atomicAdd(&stats[tid], t1);
        atomicAdd(&stats[8 + tid], t2);
        float q1 = wgn[tid] + wgn[16 + tid] + wgn[32 + tid] + wgn[48 + tid];
        float q2 = wgn[8 + tid] + wgn[24 + tid] + wgn[40 + tid] + wgn[56 + tid];
        atomicAdd(&gs[bg * 8 + tid], q1);
        atomicAdd(&gs[128 + bg * 8 + tid], q2);
    }
}

// K5: finalize BN3 scale/shift; x11 = softmax(gn_b).
__global__ void k_finalize(const float* __restrict__ stats, const float* __restrict__ g3,
                           const float* __restrict__ be3, const float* __restrict__ gnb,
                           float* __restrict__ bnp, float* __restrict__ x11) {
    int tid = threadIdx.x;
    if (tid < 8) {
        float N = 16.f * (float)VOL;
        float mean = stats[tid] / N;
        float var  = stats[8 + tid] / N - mean * mean;
        float sc = g3[tid] * rsqrtf(var + EPSF);
        bnp[tid] = sc; bnp[8 + tid] = be3[tid] - mean * sc;
    }
    if (tid == 0) {
        float m = -1e30f;
        for (int c = 0; c < 8; c++) m = fmaxf(m, gnb[c]);
        float e[8], sum = 0.f;
        for (int c = 0; c < 8; c++) { e[c] = __expf(gnb[c] - m); sum += e[c]; }
        for (int c = 0; c < 8; c++) x11[c] = e[c] / sum;
    }
}

// K6: per-row sum of relu(bn(x2h)) -> mrelu. 1024 blocks, half4 reads.
__global__ void k_relumean(const _Float16* __restrict__ x2h, const float* __restrict__ bnp,
                           float* __restrict__ mrelu) {
    int blk = blockIdx.x;
    int r = blk >> 3, part = blk & 7;
    int cc = r & 7;
    float sc = bnp[cc], sh = bnp[8 + cc];
    const half4_t* p = (const half4_t*)(x2h + (size_t)r * VOL + (size_t)part * 32768);
    int tid = threadIdx.x;
    float s = 0.f;
    for (int it = 0; it < 32; it++) {
        half4_t v = p[it * 256 + tid];
        s += fmaxf(sc * (float)v.x + sh, 0.f) + fmaxf(sc * (float)v.y + sh, 0.f)
           + fmaxf(sc * (float)v.z + sh, 0.f) + fmaxf(sc * (float)v.w + sh, 0.f);
    }
    s = waveReduceSum(s);
    __shared__ float wred[4];
    int lane = tid & 63, wid = tid >> 6;
    if (lane == 0) wred[wid] = s;
    __syncthreads();
    if (tid == 0) atomicAdd(&mrelu[r], wred[0] + wred[1] + wred[2] + wred[3]);
}

// K6b: x21[bg][c] = softmax_c(mrelu[bg*8+c]/VOL)
__global__ void k_soft21(const float* __restrict__ mrelu, float* __restrict__ x21) {
    int bg = threadIdx.x;
    if (bg < 16) {
        float v[8], m = -1e30f;
        for (int c = 0; c < 8; c++) { v[c] = mrelu[bg * 8 + c] / (float)VOL; m = fmaxf(m, v[c]); }
        float sum = 0.f;
        for (int c = 0; c < 8; c++) { v[c] = __expf(v[c] - m); sum += v[c]; }
        for (int c = 0; c < 8; c++) x21[bg * 8 + c] = v[c] / sum;
    }
}

// ---------------------------------------------------------------------------
// K7: final fused: weights = x11·x22 + x21·x12; out = x * sigmoid(weights).
// ---------------------------------------------------------------------------
__global__ void k_final(const float* __restrict__ x, const _Float16* __restrict__ x2h,
                        const float* __restrict__ a, const float* __restrict__ bnp,
                        const float* __restrict__ x11g, const float* __restrict__ x21g,
                        const float* __restrict__ gs, const float* __restrict__ gng,
                        const float* __restrict__ gnb, float* __restrict__ out) {
    int bg = blockIdx.x >> 8;
    int seg = blockIdx.x & 255;
    int tid = threadIdx.x;
    __shared__ float sa[1536];
    __shared__ float sc_[8], sh_[8], sx11[8], sx21[8], sgsc[8], sgsh[8];
    const float* ap = a + (size_t)bg * 1536;
    for (int i = tid; i < 1536; i += 256) sa[i] = ap[i];
    if (tid < 8) {
        int r = bg * 8 + tid;
        sc_[tid] = bnp[tid]; sh_[tid] = bnp[8 + tid];
        sx11[tid] = x11g[tid]; sx21[tid] = x21g[r];
        float mean = gs[r] / (float)VOL;
        float var  = gs[128 + r] / (float)VOL - mean * mean;
        float gr = rsqrtf(var + EPSF) * gng[tid];
        sgsc[tid] = gr; sgsh[tid] = gnb[tid] - mean * gr;
    }
    __syncthreads();
    int n = (seg * 256 + tid) * 4;
    int d = n >> 12, h = (n >> 6) & 63, w = n & 63;
    size_t base = ((size_t)bg << 21) + n;
    float4 xr[8];
    float w0 = 0.f, w1 = 0.f, w2 = 0.f, w3 = 0.f;
    #pragma unroll
    for (int c = 0; c < 8; c++) {
        size_t idx = base + ((size_t)c << 18);
        float4 xv = *(const float4*)(x + idx);
        half4_t v2 = *(const half4_t*)(x2h + idx);
        xr[c] = xv;
        float adh = sa[c * 192 + d] * sa[c * 192 + 64 + h] * sgsc[c];
        float x22_0 = fmaxf(sc_[c] * (float)v2.x + sh_[c], 0.f);
        float x22_1 = fmaxf(sc_[c] * (float)v2.y + sh_[c], 0.f);
        float x22_2 = fmaxf(sc_[c] * (float)v2.z + sh_[c], 0.f);
        float x22_3 = fmaxf(sc_[c] * (float)v2.w + sh_[c], 0.f);
        float x12_0 = xv.x * (adh * sa[c * 192 + 128 + w])     + sgsh[c];
        float x12_1 = xv.y * (adh * sa[c * 192 + 128 + w + 1]) + sgsh[c];
        float x12_2 = xv.z * (adh * sa[c * 192 + 128 + w + 2]) + sgsh[c];
        float x12_3 = xv.w * (adh * sa[c * 192 + 128 + w + 3]) + sgsh[c];
        w0 += sx11[c] * x22_0 + sx21[c] * x12_0;
        w1 += sx11[c] * x22_1 + sx21[c] * x12_1;
        w2 += sx11[c] * x22_2 + sx21[c] * x12_2;
        w3 += sx11[c] * x22_3 + sx21[c] * x12_3;
    }
    float s0 = 1.f / (1.f + __expf(-w0));
    float s1 = 1.f / (1.f + __expf(-w1));
    float s2 = 1.f / (1.f + __expf(-w2));
    float s3 = 1.f / (1.f + __expf(-w3));
    #pragma unroll
    for (int c = 0; c < 8; c++) {
        float4 o;
        o.x = xr[c].x * s0; o.y = xr[c].y * s1; o.z = xr[c].z * s2; o.w = xr[c].w * s3;
        *(float4*)(out + base + ((size_t)c << 18)) = o;
    }
}

extern "C" void kernel_launch(void* const* d_in, const int* in_sizes, int n_in,
                              void* d_out, int out_size, void* d_ws, size_t ws_size,
                              hipStream_t stream) {
    const float* x   = (const float*)d_in[0];
    const float* w1  = (const float*)d_in[1];
    const float* b1  = (const float*)d_in[2];
    const float* g1  = (const float*)d_in[3];
    const float* be1 = (const float*)d_in[4];
    const float* w3  = (const float*)d_in[5];
    const float* b3  = (const float*)d_in[6];
    const float* g3  = (const float*)d_in[7];
    const float* be3 = (const float*)d_in[8];
    const float* gng = (const float*)d_in[9];
    const float* gnb = (const float*)d_in[10];
    float* out = (float*)d_out;

    float* wsf       = (float*)d_ws;
    _Float16* x2h    = (_Float16*)d_ws;       // 33554432 halfs = 16777216 float-slots
    // zeroed region (contiguous): catS, stats, gs, mrelu
    float* catS   = wsf + 16777216;           // 24576
    float* stats  = catS + 24576;             // 16
    float* gs     = stats + 16;               // 256
    float* mrelu  = gs + 256;                 // 128
    // non-zeroed small buffers
    float* a      = mrelu + 128;              // 24576
    float* bnp    = a + 24576;                // 16
    float* x11    = bnp + 16;                 // 8
    float* x21    = x11 + 8;                  // 128
    float* attnp  = x21 + 128;                // 16
    _Float16* wB  = (_Float16*)(attnp + 16);  // 3584 halfs (MFMA B-fragments)

    hipMemsetAsync(catS, 0, (24576 + 16 + 256 + 128) * sizeof(float), stream);

    k_wprep     <<<14, 256, 0, stream>>>(w3, wB);
    k_pools     <<<2048, 256, 0, stream>>>(x, catS);
    k_attn_stats<<<1, 256, 0, stream>>>(catS, w1, b1, g1, be1, attnp);
    k_attn_apply<<<96, 256, 0, stream>>>(catS, w1, b1, attnp, a);
    k_conv      <<<1024, 256, 0, stream>>>(x, wB, b3, a, x2h, stats, gs);
    k_finalize  <<<1, 64, 0, stream>>>(stats, g3, be3, gnb, bnp, x11);
    k_relumean  <<<1024, 256, 0, stream>>>(x2h, bnp, mrelu);
    k_soft21    <<<1, 64, 0, stream>>>(mrelu, x21);
    k_final     <<<4096, 256, 0, stream>>>(x, x2h, a, bnp, x11, x21, gs, gng, gnb, out);
}

// Round 8
// 409.800 us; speedup vs baseline: 1.1694x; 1.0874x over previous
//
#include <hip/hip_runtime.h>
#include <math.h>
#include <stdint.h>

#define VOL 262144        // 64^3
#define EPSF 1e-5f

typedef _Float16 half4_t __attribute__((ext_vector_type(4)));
typedef _Float16 half8 __attribute__((ext_vector_type(8)));
typedef float floatx4 __attribute__((ext_vector_type(4)));

__device__ __forceinline__ float waveReduceSum(float v) {
    #pragma unroll
    for (int off = 32; off > 0; off >>= 1) v += __shfl_down(v, off);
    return v;
}

// pack two fp32 -> fp16x2 in one instr
__device__ __forceinline__ uint32_t pk2(float a, float b) {
    uint32_t r;
    asm("v_cvt_pkrtz_f16_f32 %0, %1, %2" : "=v"(r) : "v"(a), "v"(b));
    return r;
}

// barrier WITHOUT vmcnt(0) drain: LDS ops must be visible (lgkmcnt), but
// in-flight global stores (x2h) may float across. sched_barrier(0) per rule
// "inline-asm waitcnt needs a following sched_barrier" to stop hoisting.
__device__ __forceinline__ void softBarrier() {
    asm volatile("s_waitcnt lgkmcnt(0)" ::: "memory");
    __builtin_amdgcn_s_barrier();
    __builtin_amdgcn_sched_barrier(0);
}

// ---------------------------------------------------------------------------
// K0: weight prep -> MFMA B-fragments for mfma_f32_16x16x32_f16.
// wB[ks][lane][j]: k = ks*32 + (lane>>4)*8 + j maps to tap t = ks*4+(lane>>4),
// ic = j; n = lane&15 = oc (cols 8..15 zero; taps >= 27 zero).
// ---------------------------------------------------------------------------
__global__ void k_wprep(const float* __restrict__ w3, _Float16* __restrict__ wB) {
    int i = blockIdx.x * 256 + threadIdx.x;
    if (i < 3584) {
        int j = i & 7;
        int lane = (i >> 3) & 63;
        int ks = i >> 9;
        int oc = lane & 15;
        int t = ks * 4 + (lane >> 4);
        float v = 0.f;
        if (oc < 8 && t < 27) v = w3[(oc * 8 + j) * 27 + t];
        wB[i] = (_Float16)v;
    }
}

// ---------------------------------------------------------------------------
// K1: directional pool SUMS. 2048 blocks: r = blk>>4, p4 = blk&15 (4 d-slices).
// ---------------------------------------------------------------------------
__global__ void k_pools(const float* __restrict__ x, float* __restrict__ catS) {
    int r = blockIdx.x >> 4, p4 = blockIdx.x & 15;
    const float* base = x + (size_t)r * VOL + ((size_t)(p4 * 4) << 12);
    __shared__ float sd[4], sh[64], sw[64];
    int tid = threadIdx.x;
    if (tid < 4) sd[tid] = 0.f;
    if (tid < 64) { sh[tid] = 0.f; sw[tid] = 0.f; }
    __syncthreads();
    int w4 = (tid & 15) * 4;
    int hr = tid >> 4;
    int lane = tid & 63;
    float dacc[4] = {0.f, 0.f, 0.f, 0.f};
    float hacc[4] = {0.f, 0.f, 0.f, 0.f};
    float wacc[4] = {0.f, 0.f, 0.f, 0.f};
    #pragma unroll
    for (int p = 0; p < 4; p++) {
        const float* pd = base + (p << 12);
        #pragma unroll
        for (int j = 0; j < 4; j++) {
            float4 v = *(const float4*)(pd + ((hr + j * 16) << 6) + w4);
            float s = v.x + v.y + v.z + v.w;
            dacc[p] += s; hacc[j] += s;
            wacc[0] += v.x; wacc[1] += v.y; wacc[2] += v.z; wacc[3] += v.w;
        }
    }
    #pragma unroll
    for (int p = 0; p < 4; p++) {
        float s = waveReduceSum(dacc[p]);
        if (lane == 0) atomicAdd(&sd[p], s);
    }
    #pragma unroll
    for (int j = 0; j < 4; j++) {
        float hv = hacc[j];
        hv += __shfl_xor(hv, 1); hv += __shfl_xor(hv, 2);
        hv += __shfl_xor(hv, 4); hv += __shfl_xor(hv, 8);
        if ((lane & 15) == 0) atomicAdd(&sh[hr + j * 16], hv);
    }
    #pragma unroll
    for (int k = 0; k < 4; k++) {
        float wv = wacc[k];
        wv += __shfl_xor(wv, 16); wv += __shfl_xor(wv, 32);
        if (lane < 16) atomicAdd(&sw[w4 + k], wv);
    }
    __syncthreads();
    float* o = catS + (size_t)r * 192;
    if (tid < 4)                       atomicAdd(&o[p4 * 4 + tid], sd[tid]);
    else if (tid >= 64 && tid < 128)   atomicAdd(&o[64 + tid - 64], sh[tid - 64]);
    else if (tid >= 128 && tid < 192)  atomicAdd(&o[128 + tid - 128], sw[tid - 128]);
}

// ---------------------------------------------------------------------------
// K2a: BN stats of hwd. Single block. attnp[0..7]=scale, [8..15]=shift.
// ---------------------------------------------------------------------------
__global__ void k_attn_stats(const float* __restrict__ catS, const float* __restrict__ w1,
                             const float* __restrict__ b1, const float* __restrict__ g1,
                             const float* __restrict__ be1, float* __restrict__ attnp) {
    __shared__ float r1[256], r2[256];
    __shared__ float wsm[64];
    int tid = threadIdx.x;
    if (tid < 64) wsm[tid] = w1[tid] * (1.f / 4096.f);
    __syncthreads();
    int o = tid >> 5, j = tid & 31;
    float s1 = 0.f, s2 = 0.f;
    for (int idx = j; idx < 3072; idx += 32) {
        int bgI = idx / 192, s = idx - bgI * 192;
        const float* cp = catS + (size_t)bgI * 1536 + s;
        float h = b1[o];
        #pragma unroll
        for (int i = 0; i < 8; i++) h += wsm[o * 8 + i] * cp[i * 192];
        s1 += h; s2 += h * h;
    }
    r1[tid] = s1; r2[tid] = s2;
    __syncthreads();
    for (int st = 16; st > 0; st >>= 1) {
        if (j < st) { r1[tid] += r1[tid + st]; r2[tid] += r2[tid + st]; }
        __syncthreads();
    }
    if (j == 0) {
        float mean = r1[tid] / 3072.f;
        float var  = r2[tid] / 3072.f - mean * mean;
        float sc = g1[o] * rsqrtf(var + EPSF);
        attnp[o] = sc; attnp[8 + o] = be1[o] - mean * sc;
    }
}

// K2b: apply BN+relu+sigmoid -> a.
__global__ void k_attn_apply(const float* __restrict__ catS, const float* __restrict__ w1,
                             const float* __restrict__ b1, const float* __restrict__ attnp,
                             float* __restrict__ aout) {
    __shared__ float wsm[64];
    int tid = threadIdx.x;
    if (tid < 64) wsm[tid] = w1[tid] * (1.f / 4096.f);
    __syncthreads();
    int e = blockIdx.x * 256 + tid;
    int bgI = e / 1536;
    int rem = e - bgI * 1536;
    int oo = rem / 192;
    int s = rem - oo * 192;
    const float* cp = catS + (size_t)bgI * 1536 + s;
    float h = b1[oo];
    #pragma unroll
    for (int i = 0; i < 8; i++) h += wsm[oo * 8 + i] * cp[i * 192];
    float v = attnp[oo] * h + attnp[8 + oo];
    v = fmaxf(v, 0.f);
    aout[e] = 1.f / (1.f + __expf(-v));
}

// ---------------------------------------------------------------------------
// K4: 3x3x3 SAME conv as implicit GEMM on MFMA (mfma_f32_16x16x32_f16),
// GroupNorm raw sums fused into staging (R4-proven geometry: 18-row slices,
// 512 blocks, WSTRIDE 66, sA in LDS). Only delta vs R4: in-loop barriers are
// raw s_barrier + lgkmcnt(0) (no vmcnt(0) drain of the x2h stores).
// Grid 512 = bg(16) x ht(4) x dc(8). Block = 256 thr = 4 waves.
// ---------------------------------------------------------------------------
#define SLICE_B (18 * 66 * 16)   // 19008 B per d-slice

__device__ __forceinline__ void stage_slice(const float* __restrict__ xb, int dd,
                                            char* smem, int slot, int h0, int tid,
                                            const float* __restrict__ sA, int d0,
                                            float* g1, float* g2) {
    char* sb = smem + slot * SLICE_B;
    bool dok = (dd >= 0) && (dd < 64);
    bool core = (dd >= d0) && (dd < d0 + 8);
    const float* pd = xb + ((size_t)(dd & 63) << 12);
    for (int u = tid; u < 288; u += 256) {
        int hl = u >> 4;
        int w4 = (u & 15) << 2;
        int gh = h0 - 1 + hl;
        bool ok = dok && (gh >= 0) && (gh < 64);
        bool acc = core && (hl >= 1) && (hl <= 16);
        float vv[8][4];
        #pragma unroll
        for (int ic = 0; ic < 8; ic++) {
            float4 t = make_float4(0.f, 0.f, 0.f, 0.f);
            if (ok) t = *(const float4*)(pd + ((size_t)ic << 18) + (gh << 6) + w4);
            vv[ic][0] = t.x; vv[ic][1] = t.y; vv[ic][2] = t.z; vv[ic][3] = t.w;
        }
        if (acc) {
            #pragma unroll
            for (int ic = 0; ic < 8; ic++) {
                const float* Ap = sA + ic * 192;
                float ad = Ap[dd] * Ap[64 + gh];
                float y0 = vv[ic][0] * ad * Ap[128 + w4];
                float y1 = vv[ic][1] * ad * Ap[128 + w4 + 1];
                float y2 = vv[ic][2] * ad * Ap[128 + w4 + 2];
                float y3 = vv[ic][3] * ad * Ap[128 + w4 + 3];
                g1[ic] += y0 + y1 + y2 + y3;
                g2[ic] += y0 * y0 + y1 * y1 + y2 * y2 + y3 * y3;
            }
        }
        char* wp = sb + ((hl * 66) + 1 + w4) * 16;
        #pragma unroll
        for (int j = 0; j < 4; j++) {
            uint4 q;
            q.x = pk2(vv[0][j], vv[1][j]);
            q.y = pk2(vv[2][j], vv[3][j]);
            q.z = pk2(vv[4][j], vv[5][j]);
            q.w = pk2(vv[6][j], vv[7][j]);
            *(uint4*)(wp + j * 16) = q;
        }
    }
}

__global__ __launch_bounds__(256) void k_conv(const float* __restrict__ x,
                                              const _Float16* __restrict__ wB,
                                              const float* __restrict__ b3,
                                              const float* __restrict__ a,
                                              _Float16* __restrict__ x2h,
                                              float* __restrict__ stats,
                                              float* __restrict__ gs) {
    __shared__ __align__(16) char smem[3 * SLICE_B + 768 + 6144];
    float* wred = (float*)(smem + 3 * SLICE_B);         // 128 floats (BN)
    float* wgn  = wred + 128;                           // 64 floats (GN)
    float* sA   = (float*)(smem + 3 * SLICE_B + 768);   // 8 x 192 floats
    int blk = blockIdx.x;
    int bg = blk >> 5;
    int rem = blk & 31;
    int ht = rem >> 3;
    int dc = rem & 7;
    int h0 = ht << 4;
    int d0 = dc << 3;
    int tid = threadIdx.x;
    int lane = tid & 63, wid = tid >> 6;
    int lm = lane & 15, lg = lane >> 4;
    const float* xb = x + ((size_t)bg << 21);

    // B fragments (7 k-steps x 16B/lane)
    half8 bfr[7];
    #pragma unroll
    for (int ks = 0; ks < 7; ks++)
        bfr[ks] = *(const half8*)(wB + (ks << 9) + (lane << 3));

    float b3v = (lm < 8) ? b3[lm] : 0.f;

    // per-lane tap -> LDS relative offsets (ky,kx,lm folded; wid folds h base)
    int rel[7], kzv[7];
    #pragma unroll
    for (int ks = 0; ks < 7; ks++) {
        int t = ks * 4 + lg; if (t > 26) t = 26;   // pad tap: B rows are zero
        int kz = t / 9, r9 = t - kz * 9;
        int ky = r9 / 3, kx = r9 - ky * 3;
        kzv[ks] = kz;
        rel[ks] = (((ky + wid * 4) * 66) + kx + lm) << 4;
    }

    // zero halo columns (wl = 0, 65) of all 3 slots, once
    for (int u = tid; u < 108; u += 256) {
        int s = u / 36, r2 = u - s * 36;
        int hh = r2 >> 1, side = r2 & 1;
        uint4 z; z.x = 0; z.y = 0; z.z = 0; z.w = 0;
        *(uint4*)(smem + s * SLICE_B + ((hh * 66) + side * 65) * 16) = z;
    }
    // attention profiles for this bg (8 rows x 192)
    for (int i = tid; i < 1536; i += 256) sA[i] = a[(size_t)bg * 1536 + i];
    __syncthreads();   // sA ready before staging accumulates GN sums

    size_t eb = (((size_t)(bg * 8 + lm)) << 18) + ((size_t)(h0 + wid * 4) << 6) + (lg << 2);
    bool ocok = lm < 8;
    float ps = 0.f, pq = 0.f;
    float g1[8] = {0.f, 0.f, 0.f, 0.f, 0.f, 0.f, 0.f, 0.f};
    float g2[8] = {0.f, 0.f, 0.f, 0.f, 0.f, 0.f, 0.f, 0.f};

    stage_slice(xb, d0 - 1, smem, (d0 + 2) % 3, h0, tid, sA, d0, g1, g2);
    stage_slice(xb, d0,     smem, d0 % 3,       h0, tid, sA, d0, g1, g2);
    __syncthreads();

    for (int i = 0; i < 8; i++) {
        int d = d0 + i;
        stage_slice(xb, d + 1, smem, (d + 1) % 3, h0, tid, sA, d0, g1, g2);
        softBarrier();   // ds_writes visible; x2h stores NOT drained
        int u0 = ((d + 2) % 3) * SLICE_B;   // slice dd = d-1
        int u1 = (d % 3) * SLICE_B;         // slice dd = d
        int u2 = ((d + 1) % 3) * SLICE_B;   // slice dd = d+1
        int ab[7];
        #pragma unroll
        for (int ks = 0; ks < 7; ks++)
            ab[ks] = (kzv[ks] == 0 ? u0 : (kzv[ks] == 1 ? u1 : u2)) + rel[ks];
        #pragma unroll
        for (int ri = 0; ri < 4; ri++) {
            #pragma unroll
            for (int wt = 0; wt < 4; wt++) {
                floatx4 acc = {b3v, b3v, b3v, b3v};
                #pragma unroll
                for (int ks = 0; ks < 7; ks++) {
                    half8 af = *(const half8*)(smem + ab[ks] + ((ri * 66 + wt * 16) << 4));
                    acc = __builtin_amdgcn_mfma_f32_16x16x32_f16(af, bfr[ks], acc, 0, 0, 0);
                }
                uint32_t q0 = pk2(acc[0], acc[1]);
                uint32_t q1 = pk2(acc[2], acc[3]);
                if (ocok) {
                    uint2 st; st.x = q0; st.y = q1;
                    *(uint2*)(x2h + eb + ((size_t)d << 12) + (ri << 6) + (wt << 4)) = st;
                }
                ps += acc[0] + acc[1] + acc[2] + acc[3];
                pq += acc[0] * acc[0] + acc[1] * acc[1] + acc[2] * acc[2] + acc[3] * acc[3];
            }
        }
        softBarrier();   // all reads of slot (d-1) done before next stage
    }

    // BN sums: lane's oc = lm; reduce the 4 lg-replica groups, then cross-wave
    ps += __shfl_xor(ps, 16); ps += __shfl_xor(ps, 32);
    pq += __shfl_xor(pq, 16); pq += __shfl_xor(pq, 32);
    if (lane < 16) { wred[wid * 32 + lm] = ps; wred[wid * 32 + 16 + lm] = pq; }
    // GN sums: full-wave reduce per ic, then cross-wave via LDS
    #pragma unroll
    for (int ic = 0; ic < 8; ic++) {
        float r1v = waveReduceSum(g1[ic]);
        float r2v = waveReduceSum(g2[ic]);
        if (lane == 0) { wgn[wid * 16 + ic] = r1v; wgn[wid * 16 + 8 + ic] = r2v; }
    }
    __syncthreads();
    if (tid < 8) {
        float t1 = wred[tid] + wred[32 + tid] + wred[64 + tid] + wred[96 + tid];
        float t2 = wred[16 + tid] + wred[48 + tid] + wred[80 + tid] + wred[112 + tid];
        atomicAdd(&stats[tid], t1);
        atomicAdd(&stats[8 + tid], t2);
        float q1 = wgn[tid] + wgn[16 + tid] + wgn[32 + tid] + wgn[48 + tid];
        float q2 = wgn[8 + tid] + wgn[24 + tid] + wgn[40 + tid] + wgn[56 + tid];
        atomicAdd(&gs[bg * 8 + tid], q1);
        atomicAdd(&gs[128 + bg * 8 + tid], q2);
    }
}

// K5: finalize BN3 scale/shift; x11 = softmax(gn_b).
__global__ void k_finalize(const float* __restrict__ stats, const float* __restrict__ g3,
                           const float* __restrict__ be3, const float* __restrict__ gnb,
                           float* __restrict__ bnp, float* __restrict__ x11) {
    int tid = threadIdx.x;
    if (tid < 8) {
        float N = 16.f * (float)VOL;
        float mean = stats[tid] / N;
        float var  = stats[8 + tid] / N - mean * mean;
        float sc = g3[tid] * rsqrtf(var + EPSF);
        bnp[tid] = sc; bnp[8 + tid] = be3[tid] - mean * sc;
    }
    if (tid == 0) {
        float m = -1e30f;
        for (int c = 0; c < 8; c++) m = fmaxf(m, gnb[c]);
        float e[8], sum = 0.f;
        for (int c = 0; c < 8; c++) { e[c] = __expf(gnb[c] - m); sum += e[c]; }
        for (int c = 0; c < 8; c++) x11[c] = e[c] / sum;
    }
}

// K6: per-row sum of relu(bn(x2h)) -> mrelu. 1024 blocks, half4 reads.
__global__ void k_relumean(const _Float16* __restrict__ x2h, const float* __restrict__ bnp,
                           float* __restrict__ mrelu) {
    int blk = blockIdx.x;
    int r = blk >> 3, part = blk & 7;
    int cc = r & 7;
    float sc = bnp[cc], sh = bnp[8 + cc];
    const half4_t* p = (const half4_t*)(x2h + (size_t)r * VOL + (size_t)part * 32768);
    int tid = threadIdx.x;
    float s = 0.f;
    for (int it = 0; it < 32; it++) {
        half4_t v = p[it * 256 + tid];
        s += fmaxf(sc * (float)v.x + sh, 0.f) + fmaxf(sc * (float)v.y + sh, 0.f)
           + fmaxf(sc * (float)v.z + sh, 0.f) + fmaxf(sc * (float)v.w + sh, 0.f);
    }
    s = waveReduceSum(s);
    __shared__ float wred[4];
    int lane = tid & 63, wid = tid >> 6;
    if (lane == 0) wred[wid] = s;
    __syncthreads();
    if (tid == 0) atomicAdd(&mrelu[r], wred[0] + wred[1] + wred[2] + wred[3]);
}

// K6b: x21[bg][c] = softmax_c(mrelu[bg*8+c]/VOL)
__global__ void k_soft21(const float* __restrict__ mrelu, float* __restrict__ x21) {
    int bg = threadIdx.x;
    if (bg < 16) {
        float v[8], m = -1e30f;
        for (int c = 0; c < 8; c++) { v[c] = mrelu[bg * 8 + c] / (float)VOL; m = fmaxf(m, v[c]); }
        float sum = 0.f;
        for (int c = 0; c < 8; c++) { v[c] = __expf(v[c] - m); sum += v[c]; }
        for (int c = 0; c < 8; c++) x21[bg * 8 + c] = v[c] / sum;
    }
}

// ---------------------------------------------------------------------------
// K7: final fused: weights = x11·x22 + x21·x12; out = x * sigmoid(weights).
// ---------------------------------------------------------------------------
__global__ void k_final(const float* __restrict__ x, const _Float16* __restrict__ x2h,
                        const float* __restrict__ a, const float* __restrict__ bnp,
                        const float* __restrict__ x11g, const float* __restrict__ x21g,
                        const float* __restrict__ gs, const float* __restrict__ gng,
                        const float* __restrict__ gnb, float* __restrict__ out) {
    int bg = blockIdx.x >> 8;
    int seg = blockIdx.x & 255;
    int tid = threadIdx.x;
    __shared__ float sa[1536];
    __shared__ float sc_[8], sh_[8], sx11[8], sx21[8], sgsc[8], sgsh[8];
    const float* ap = a + (size_t)bg * 1536;
    for (int i = tid; i < 1536; i += 256) sa[i] = ap[i];
    if (tid < 8) {
        int r = bg * 8 + tid;
        sc_[tid] = bnp[tid]; sh_[tid] = bnp[8 + tid];
        sx11[tid] = x11g[tid]; sx21[tid] = x21g[r];
        float mean = gs[r] / (float)VOL;
        float var  = gs[128 + r] / (float)VOL - mean * mean;
        float gr = rsqrtf(var + EPSF) * gng[tid];
        sgsc[tid] = gr; sgsh[tid] = gnb[tid] - mean * gr;
    }
    __syncthreads();
    int n = (seg * 256 + tid) * 4;
    int d = n >> 12, h = (n >> 6) & 63, w = n & 63;
    size_t base = ((size_t)bg << 21) + n;
    float4 xr[8];
    float w0 = 0.f, w1 = 0.f, w2 = 0.f, w3 = 0.f;
    #pragma unroll
    for (int c = 0; c < 8; c++) {
        size_t idx = base + ((size_t)c << 18);
        float4 xv = *(const float4*)(x + idx);
        half4_t v2 = *(const half4_t*)(x2h + idx);
        xr[c] = xv;
        float adh = sa[c * 192 + d] * sa[c * 192 + 64 + h] * sgsc[c];
        float x22_0 = fmaxf(sc_[c] * (float)v2.x + sh_[c], 0.f);
        float x22_1 = fmaxf(sc_[c] * (float)v2.y + sh_[c], 0.f);
        float x22_2 = fmaxf(sc_[c] * (float)v2.z + sh_[c], 0.f);
        float x22_3 = fmaxf(sc_[c] * (float)v2.w + sh_[c], 0.f);
        float x12_0 = xv.x * (adh * sa[c * 192 + 128 + w])     + sgsh[c];
        float x12_1 = xv.y * (adh * sa[c * 192 + 128 + w + 1]) + sgsh[c];
        float x12_2 = xv.z * (adh * sa[c * 192 + 128 + w + 2]) + sgsh[c];
        float x12_3 = xv.w * (adh * sa[c * 192 + 128 + w + 3]) + sgsh[c];
        w0 += sx11[c] * x22_0 + sx21[c] * x12_0;
        w1 += sx11[c] * x22_1 + sx21[c] * x12_1;
        w2 += sx11[c] * x22_2 + sx21[c] * x12_2;
        w3 += sx11[c] * x22_3 + sx21[c] * x12_3;
    }
    float s0 = 1.f / (1.f + __expf(-w0));
    float s1 = 1.f / (1.f + __expf(-w1));
    float s2 = 1.f / (1.f + __expf(-w2));
    float s3 = 1.f / (1.f + __expf(-w3));
    #pragma unroll
    for (int c = 0; c < 8; c++) {
        float4 o;
        o.x = xr[c].x * s0; o.y = xr[c].y * s1; o.z = xr[c].z * s2; o.w = xr[c].w * s3;
        *(float4*)(out + base + ((size_t)c << 18)) = o;
    }
}

extern "C" void kernel_launch(void* const* d_in, const int* in_sizes, int n_in,
                              void* d_out, int out_size, void* d_ws, size_t ws_size,
                              hipStream_t stream) {
    const float* x   = (const float*)d_in[0];
    const float* w1  = (const float*)d_in[1];
    const float* b1  = (const float*)d_in[2];
    const float* g1  = (const float*)d_in[3];
    const float* be1 = (const float*)d_in[4];
    const float* w3  = (const float*)d_in[5];
    const float* b3  = (const float*)d_in[6];
    const float* g3  = (const float*)d_in[7];
    const float* be3 = (const float*)d_in[8];
    const float* gng = (const float*)d_in[9];
    const float* gnb = (const float*)d_in[10];
    float* out = (float*)d_out;

    float* wsf       = (float*)d_ws;
    _Float16* x2h    = (_Float16*)d_ws;       // 33554432 halfs = 16777216 float-slots
    // zeroed region (contiguous): catS, stats, gs, mrelu
    float* catS   = wsf + 16777216;           // 24576
    float* stats  = catS + 24576;             // 16
    float* gs     = stats + 16;               // 256
    float* mrelu  = gs + 256;                 // 128
    // non-zeroed small buffers
    float* a      = mrelu + 128;              // 24576
    float* bnp    = a + 24576;                // 16
    float* x11    = bnp + 16;                 // 8
    float* x21    = x11 + 8;                  // 128
    float* attnp  = x21 + 128;                // 16
    _Float16* wB  = (_Float16*)(attnp + 16);  // 3584 halfs (MFMA B-fragments)

    hipMemsetAsync(catS, 0, (24576 + 16 + 256 + 128) * sizeof(float), stream);

    k_wprep     <<<14, 256, 0, stream>>>(w3, wB);
    k_pools     <<<2048, 256, 0, stream>>>(x, catS);
    k_attn_stats<<<1, 256, 0, stream>>>(catS, w1, b1, g1, be1, attnp);
    k_attn_apply<<<96, 256, 0, stream>>>(catS, w1, b1, attnp, a);
    k_conv      <<<512, 256, 0, stream>>>(x, wB, b3, a, x2h, stats, gs);
    k_finalize  <<<1, 64, 0, stream>>>(stats, g3, be3, gnb, bnp, x11);
    k_relumean  <<<1024, 256, 0, stream>>>(x2h, bnp, mrelu);
    k_soft21    <<<1, 64, 0, stream>>>(mrelu, x21);
    k_final     <<<4096, 256, 0, stream>>>(x, x2h, a, bnp, x11, x21, gs, gng, gnb, out);
}